// Round 15
// baseline (326.088 us; speedup 1.0000x reference)
//
#include <hip/hip_runtime.h>

#define NNODES 50000
#define NEDGES 800000
#define DIM 128
#define NGRAPHS 256
#define NPAD 50176      // 196*256, padded node count for int arrays
#define SCAN_BLOCKS 196
#define NXCD 8
#define NODES_PER_XCD (NNODES / NXCD)   // 6250
#define GB 391                           // blocks per XCD group (bucket)
#define EPB 2048                         // edges per block chunk (256 thr x 8)

typedef _Float16 half8_t __attribute__((ext_vector_type(8)));
typedef float f32x4 __attribute__((ext_vector_type(4)));

// ---------------- fused prep: cast x->f16, build WT1/WT2, 1-pass histogram ----------------
// grid = 3125 x 256 (= 800000 threads). Histogram atomics are device-scope
// (memory-side) regardless of XCD, so 1 pass / 1 atomic per edge is optimal.
__global__ void prep_kernel(const float* __restrict__ x, _Float16* __restrict__ xh,
                            const float* __restrict__ w1_rel, const float* __restrict__ w1_root,
                            const float* __restrict__ w2_rel, const float* __restrict__ w2_root,
                            _Float16* __restrict__ WT1, _Float16* __restrict__ WT2,
                            const int* __restrict__ dst, int* __restrict__ deg) {
    int tid = blockIdx.x * 256 + threadIdx.x;

    // ---- cast x (8 f32 -> 8 f16 per thread), tid < 800000 ----
    if (tid < (NNODES * DIM / 8)) {
        const float4* x4 = reinterpret_cast<const float4*>(x);
        float4 a = x4[tid * 2];
        float4 b = x4[tid * 2 + 1];
        half8_t h;
        h[0] = (_Float16)a.x; h[1] = (_Float16)a.y; h[2] = (_Float16)a.z; h[3] = (_Float16)a.w;
        h[4] = (_Float16)b.x; h[5] = (_Float16)b.y; h[6] = (_Float16)b.z; h[7] = (_Float16)b.w;
        *reinterpret_cast<half8_t*>(&xh[(size_t)tid * 8]) = h;
    }

    // ---- cast/transpose weights, tid < 65536 ----
    if (tid < 2 * DIM * 256) {
        int layer = tid >> 15;
        int r = tid & 32767;
        int c = r >> 8;        // 0..127 output col
        int k = r & 255;       // 0..255 combined K
        const float* wr = layer ? w2_rel : w1_rel;
        const float* wo = layer ? w2_root : w1_root;
        float v = (k < 128) ? wr[k * DIM + c] : wo[(k - 128) * DIM + c];
        _Float16* dstp = layer ? WT2 : WT1;
        dstp[(size_t)c * 256 + k] = (_Float16)v;
    }

    // ---- 1-pass histogram: one edge, one fire-and-forget atomic ----
    if (tid < NEDGES) atomicAdd(&deg[dst[tid]], 1);
}

// ---------------- 3-phase exclusive scan over deg[NPAD] ----------------
__global__ void scan1_kernel(const int* __restrict__ deg, int* __restrict__ bsum) {
    __shared__ int s[256];
    int t = threadIdx.x;
    s[t] = deg[blockIdx.x * 256 + t];
    __syncthreads();
    #pragma unroll
    for (int d = 128; d > 0; d >>= 1) {
        if (t < d) s[t] += s[t + d];
        __syncthreads();
    }
    if (t == 0) bsum[blockIdx.x] = s[0];
}

__global__ void scan2_kernel(int* __restrict__ bsum) {
    __shared__ int s[256];
    int t = threadIdx.x;
    int v = (t < SCAN_BLOCKS) ? bsum[t] : 0;
    s[t] = v;
    __syncthreads();
    #pragma unroll
    for (int d = 1; d < 256; d <<= 1) {
        int u = (t >= d) ? s[t - d] : 0;
        __syncthreads();
        s[t] += u;
        __syncthreads();
    }
    if (t < SCAN_BLOCKS) bsum[t] = (t == 0) ? 0 : s[t - 1];
}

__global__ void scan3_kernel(const int* __restrict__ deg,
                             const int* __restrict__ bsum,
                             int* __restrict__ offs,
                             int* __restrict__ curs) {
    __shared__ int s[256];
    int t = threadIdx.x;
    int idx = blockIdx.x * 256 + t;
    s[t] = deg[idx];
    __syncthreads();
    #pragma unroll
    for (int d = 1; d < 256; d <<= 1) {
        int u = (t >= d) ? s[t - d] : 0;
        __syncthreads();
        s[t] += u;
        __syncthreads();
    }
    int excl = ((t == 0) ? 0 : s[t - 1]) + bsum[blockIdx.x];
    if (idx <= NNODES) {
        offs[idx] = excl;
        curs[idx] = excl;
    }
}

// ---------------- bucket edges by dst, XCD-localized ----------------
// group g (= blockIdx%8, lands on XCD g) commits only its dst-range: the CSR
// scatter STORES for that range stay in ONE XCD's L2 (400 KB window) -> full-line
// evictions instead of 8-way partial-line churn. (Verified R13: bucket left top-5.)
__global__ void bucket_kernel(const int* __restrict__ src,
                              const int* __restrict__ dst,
                              int* __restrict__ curs,
                              int* __restrict__ srcs_sorted) {
    int g  = blockIdx.x & (NXCD - 1);
    int bb = blockIdx.x >> 3;
    int lo = g * NODES_PER_XCD, hi = lo + NODES_PER_XCD;
    int base = bb * EPB + threadIdx.x;
    #pragma unroll
    for (int i = 0; i < 8; ++i) {
        int e = base + i * 256;
        if (e < NEDGES) {
            int d = dst[e];
            if (d >= lo && d < hi) {
                int pos = atomicAdd(&curs[d], 1);
                srcs_sorted[pos] = src[e];
            }
        }
    }
}

// ---------------- gather-aggregate (f16 in, f16 out, f32 accum) ----------------
// 16 lanes per node (half8 = 16B each), 16 nodes per 256-thread block.
// 4-deep neighbor unroll for ILP. No atomics.
__global__ void gather_agg_kernel(const _Float16* __restrict__ feat,
                                  const int* __restrict__ offs,
                                  const int* __restrict__ srcs_sorted,
                                  _Float16* __restrict__ agg) {
    int n = blockIdx.x * 16 + (threadIdx.x >> 4);
    int q = threadIdx.x & 15;
    if (n >= NNODES) return;
    int beg = offs[n], end = offs[n + 1];
    float a0[8] = {0.f, 0.f, 0.f, 0.f, 0.f, 0.f, 0.f, 0.f};
    float a1[8] = {0.f, 0.f, 0.f, 0.f, 0.f, 0.f, 0.f, 0.f};
    int i = beg;
    for (; i + 4 <= end; i += 4) {
        int s0 = srcs_sorted[i + 0];
        int s1 = srcs_sorted[i + 1];
        int s2 = srcs_sorted[i + 2];
        int s3 = srcs_sorted[i + 3];
        half8_t v0 = *reinterpret_cast<const half8_t*>(&feat[(size_t)s0 * DIM + q * 8]);
        half8_t v1 = *reinterpret_cast<const half8_t*>(&feat[(size_t)s1 * DIM + q * 8]);
        half8_t v2 = *reinterpret_cast<const half8_t*>(&feat[(size_t)s2 * DIM + q * 8]);
        half8_t v3 = *reinterpret_cast<const half8_t*>(&feat[(size_t)s3 * DIM + q * 8]);
        #pragma unroll
        for (int j = 0; j < 8; ++j) {
            a0[j] += (float)v0[j] + (float)v1[j];
            a1[j] += (float)v2[j] + (float)v3[j];
        }
    }
    for (; i < end; ++i) {
        half8_t v = *reinterpret_cast<const half8_t*>(&feat[(size_t)srcs_sorted[i] * DIM + q * 8]);
        #pragma unroll
        for (int j = 0; j < 8; ++j) a0[j] += (float)v[j];
    }
    half8_t r;
    #pragma unroll
    for (int j = 0; j < 8; ++j) r[j] = (_Float16)(a0[j] + a1[j]);
    *reinterpret_cast<half8_t*>(&agg[(size_t)n * DIM + q * 8]) = r;
}

// ------------- GraphConv dense part via fp16 MFMA -------------
// out = relu([Ah|Xh] @ WT^T + b), K=256 combined. Block = 4 waves = 128 rows.
// Per wave: 32 rows x 128 cols = 2 Msub x 8 Ntiles of 16x16x32 MFMA, f32 accum.
// No LDS: A/B frags via L1/L2. Xh/outh may alias (layer2 in-place): each block
// reads only its own rows and all reads precede its writes.
__global__ __launch_bounds__(256) void conv_mfma_kernel(
        const _Float16* __restrict__ Ah,
        const _Float16* Xh,
        const _Float16* __restrict__ WT,   // [128 cols][256 k]
        const float* __restrict__ bias,    // [128]
        _Float16* outh) {
    const int wave = threadIdx.x >> 6;
    const int lane = threadIdx.x & 63;
    const int row0 = blockIdx.x * 128 + wave * 32;
    const int rA = lane & 15;
    const int kg = lane >> 4;          // 0..3, k-group of 8

    f32x4 acc[2][8];
    #pragma unroll
    for (int m = 0; m < 2; ++m)
        #pragma unroll
        for (int nt = 0; nt < 8; ++nt)
            acc[m][nt] = (f32x4){0.f, 0.f, 0.f, 0.f};

    int ra0 = row0 + rA;        if (ra0 > NNODES - 1) ra0 = NNODES - 1;
    int ra1 = row0 + 16 + rA;   if (ra1 > NNODES - 1) ra1 = NNODES - 1;

    #pragma unroll
    for (int ks = 0; ks < 8; ++ks) {
        const _Float16* srcb = (ks < 4) ? Ah : Xh;
        const int klocal = (ks & 3) * 32 + kg * 8;
        half8_t a0 = *reinterpret_cast<const half8_t*>(&srcb[(size_t)ra0 * DIM + klocal]);
        half8_t a1 = *reinterpret_cast<const half8_t*>(&srcb[(size_t)ra1 * DIM + klocal]);
        const int kglob = ks * 32 + kg * 8;
        #pragma unroll
        for (int nt = 0; nt < 8; ++nt) {
            half8_t b = *reinterpret_cast<const half8_t*>(&WT[(size_t)(nt * 16 + rA) * 256 + kglob]);
            acc[0][nt] = __builtin_amdgcn_mfma_f32_16x16x32_f16(a0, b, acc[0][nt], 0, 0, 0);
            acc[1][nt] = __builtin_amdgcn_mfma_f32_16x16x32_f16(a1, b, acc[1][nt], 0, 0, 0);
        }
    }

    // C/D layout (HW-verified): col = lane&15, row = (lane>>4)*4 + reg
    const int ccol = lane & 15;
    const int crow4 = (lane >> 4) * 4;
    #pragma unroll
    for (int m = 0; m < 2; ++m) {
        #pragma unroll
        for (int nt = 0; nt < 8; ++nt) {
            float bb = bias[nt * 16 + ccol];
            #pragma unroll
            for (int r = 0; r < 4; ++r) {
                int row = row0 + m * 16 + crow4 + r;
                if (row < NNODES) {
                    float v = acc[m][nt][r] + bb;
                    outh[(size_t)row * DIM + nt * 16 + ccol] = (_Float16)(v > 0.f ? v : 0.f);
                }
            }
        }
    }
}

// ---------------- fused mean-pool + MLP: out[g] = relu(mean_g(h)@fc1+b1)@fc2 + b2 ----------------
__global__ void pool_mlp_kernel(const _Float16* __restrict__ h,
                                const int* __restrict__ batch,
                                const float* __restrict__ fc1_w,
                                const float* __restrict__ fc1_b,
                                const float* __restrict__ fc2_w,
                                const float* __restrict__ fc2_b,
                                float* __restrict__ out) {
    __shared__ float p[DIM];
    __shared__ float red[DIM];
    int g = blockIdx.x;
    int c = threadIdx.x;  // 0..127
    int lo = 0, hi = NNODES;
    while (lo < hi) { int m = (lo + hi) >> 1; if (batch[m] < g) lo = m + 1; else hi = m; }
    int beg = lo;
    hi = NNODES;
    while (lo < hi) { int m = (lo + hi) >> 1; if (batch[m] < g + 1) lo = m + 1; else hi = m; }
    int end = lo;
    float acc0 = 0.f, acc1 = 0.f;
    int n = beg;
    for (; n + 2 <= end; n += 2) {
        acc0 += (float)h[(size_t)n * DIM + c];
        acc1 += (float)h[(size_t)(n + 1) * DIM + c];
    }
    if (n < end) acc0 += (float)h[(size_t)n * DIM + c];
    float cnt = (float)(end - beg);
    p[c] = (acc0 + acc1) / fmaxf(cnt, 1.f);
    __syncthreads();
    float acc = fc1_b[c];
    for (int k = 0; k < DIM; ++k) acc = fmaf(p[k], fc1_w[k * DIM + c], acc);
    acc = acc > 0.f ? acc : 0.f;
    red[c] = acc * fc2_w[c];
    __syncthreads();
    #pragma unroll
    for (int s = 64; s > 0; s >>= 1) {
        if (c < s) red[c] += red[c + s];
        __syncthreads();
    }
    if (c == 0) out[g] = red[0] + fc2_b[0];
}

extern "C" void kernel_launch(void* const* d_in, const int* in_sizes, int n_in,
                              void* d_out, int out_size, void* d_ws, size_t ws_size,
                              hipStream_t stream) {
    const float* x       = (const float*)d_in[0];
    const int*   ei      = (const int*)d_in[1];
    const int*   batch   = (const int*)d_in[2];
    const float* w1_rel  = (const float*)d_in[3];
    const float* b1_rel  = (const float*)d_in[4];
    const float* w1_root = (const float*)d_in[5];
    const float* w2_rel  = (const float*)d_in[6];
    const float* b2_rel  = (const float*)d_in[7];
    const float* w2_root = (const float*)d_in[8];
    const float* fc1_w   = (const float*)d_in[9];
    const float* fc1_b   = (const float*)d_in[10];
    const float* fc2_w   = (const float*)d_in[11];
    const float* fc2_b   = (const float*)d_in[12];
    float* out = (float*)d_out;

    char* ws = (char*)d_ws;
    const size_t feath_bytes = (size_t)NNODES * DIM * sizeof(_Float16);  // 12.8 MB
    _Float16* Ah  = (_Float16*)ws;                                   // agg buffer (f16)
    _Float16* Hh  = (_Float16*)(ws + feath_bytes);                   // activations (f16)
    _Float16* xh  = (_Float16*)(ws + 2 * feath_bytes);               // x cast (f16)
    _Float16* WT1 = (_Float16*)(ws + 3 * feath_bytes);               // [128][256] f16
    _Float16* WT2 = WT1 + 128 * 256;
    int*   deg    = (int*)(WT2 + 128 * 256);       // [NPAD]
    int*   offs   = deg + NPAD;                    // [NPAD]
    int*   curs   = offs + NPAD;                   // [NPAD]
    int*   bsum   = curs + NPAD;                   // [256]
    int*   srcs   = bsum + 256;                    // [NEDGES]

    const int* src = ei;           // edge_index[0]
    const int* dst = ei + NEDGES;  // edge_index[1]

    const int prep_blocks = (NEDGES + 255) / 256;   // 3125 (covers cast + hist)
    const int xcd_blocks  = GB * NXCD;              // 3128 (bucket)
    const int conv_blocks = (NNODES + 127) / 128;   // 391
    const int agg_blocks  = (NNODES + 15) / 16;     // 3125

    // ---- prep: casts + 1-pass histogram (deg zeroed first) ----
    hipMemsetAsync(deg, 0, NPAD * sizeof(int), stream);
    prep_kernel<<<prep_blocks, 256, 0, stream>>>(x, xh, w1_rel, w1_root, w2_rel, w2_root,
                                                 WT1, WT2, dst, deg);

    // ---- CSR offsets + XCD-localized bucket scatter ----
    scan1_kernel<<<SCAN_BLOCKS, 256, 0, stream>>>(deg, bsum);
    scan2_kernel<<<1, 256, 0, stream>>>(bsum);
    scan3_kernel<<<SCAN_BLOCKS, 256, 0, stream>>>(deg, bsum, offs, curs);
    bucket_kernel<<<xcd_blocks, 256, 0, stream>>>(src, dst, curs, srcs);

    // ---- layer 1 ----
    gather_agg_kernel<<<agg_blocks, 256, 0, stream>>>(xh, offs, srcs, Ah);
    conv_mfma_kernel<<<conv_blocks, 256, 0, stream>>>(Ah, xh, WT1, b1_rel, Hh);

    // ---- layer 2 (in-place on Hh) ----
    gather_agg_kernel<<<agg_blocks, 256, 0, stream>>>(Hh, offs, srcs, Ah);
    conv_mfma_kernel<<<conv_blocks, 256, 0, stream>>>(Ah, Hh, WT2, b2_rel, Hh);

    // ---- fused pool + MLP ----
    pool_mlp_kernel<<<NGRAPHS, 128, 0, stream>>>(Hh, batch, fc1_w, fc1_b, fc2_w, fc2_b, out);
}